// Round 1
// baseline (229.150 us; speedup 1.0000x reference)
//
#include <hip/hip_runtime.h>
#include <math.h>

#define FFT_N  2048
#define SEQ_L  1024
#define NT     256
#define LOG2N  11
#define NB     16
#define NH     512

__device__ __forceinline__ float2 c_mul(float2 a, float2 b) {
    return make_float2(a.x * b.x - a.y * b.y, a.x * b.y + a.y * b.x);
}

// Radix-2 Stockham autosort FFT over LDS ping-pong buffers.
// SIGN=-1: forward DFT. SIGN=+1: conjugate twiddles (unnormalized inverse).
// Returns pointer to the buffer holding the result. Caller must have synced
// after filling src. Result-visibility sync is done inside.
template <int SIGN>
__device__ __forceinline__ float2* fft_stockham(float2* src, float2* dst,
                                                const float2* __restrict__ tw,
                                                int tid) {
    for (int t = 0; t < LOG2N; ++t) {
        const int s = 1 << t;
#pragma unroll
        for (int it = 0; it < (FFT_N / 2) / NT; ++it) {
            const int i   = tid + it * NT;
            const int q   = i & (s - 1);
            const int pst = i ^ q;  // (i / s) * s == p << t
            float2 a = src[i];
            float2 b = src[i + FFT_N / 2];
            float2 w = tw[pst];
            if (SIGN > 0) w.y = -w.y;
            float2 sum = make_float2(a.x + b.x, a.y + b.y);
            float2 dif = make_float2(a.x - b.x, a.y - b.y);
            const int j0 = q + (pst << 1);
            dst[j0]     = sum;
            dst[j0 + s] = c_mul(dif, w);
        }
        __syncthreads();
        float2* tmp = src; src = dst; dst = tmp;
    }
    return src;  // after final swap, src holds the result
}

__device__ __forceinline__ void init_tw(float2* tw, int tid) {
#pragma unroll
    for (int it = 0; it < (FFT_N / 2) / NT; ++it) {
        const int j = tid + it * NT;
        const float ang = -6.283185307179586f * (float)j / (float)FFT_N;
        float sv, cv;
        sincosf(ang, &sv, &cv);
        tw[j] = make_float2(cv, sv);
    }
}

// ---- Kernel 1: k_f[h] = FFT_2048(pad(k[h])) -> workspace ----
__global__ __launch_bounds__(NT) void kfft_kernel(const float* __restrict__ kin,
                                                  float2* __restrict__ kf) {
    __shared__ float2 bufA[FFT_N];
    __shared__ float2 bufB[FFT_N];
    __shared__ float2 tw[FFT_N / 2];
    const int tid = threadIdx.x;
    const int h = blockIdx.x;
    init_tw(tw, tid);
    const float* krow = kin + (size_t)h * SEQ_L;
#pragma unroll
    for (int it = 0; it < FFT_N / NT; ++it) {
        const int j = tid + it * NT;
        float v = (it < SEQ_L / NT) ? krow[j] : 0.f;
        bufA[j] = make_float2(v, 0.f);
    }
    __syncthreads();
    float2* r = fft_stockham<-1>(bufA, bufB, tw, tid);
    float2* out = kf + (size_t)h * FFT_N;
#pragma unroll
    for (int it = 0; it < FFT_N / NT; ++it) {
        const int j = tid + it * NT;
        out[j] = r[j];
    }
}

// ---- Kernel 2: per (b,h) row: FFT(u) * k_f -> IFFT -> +u*D ----
__global__ __launch_bounds__(NT) void conv_kernel(const float* __restrict__ u,
                                                  const float* __restrict__ D,
                                                  const float2* __restrict__ kf,
                                                  float* __restrict__ out) {
    __shared__ float2 bufA[FFT_N];
    __shared__ float2 bufB[FFT_N];
    __shared__ float2 tw[FFT_N / 2];
    const int tid = threadIdx.x;
    const int row = blockIdx.x;       // b*NH + h
    const int h = row & (NH - 1);
    init_tw(tw, tid);
    const float* urow = u + (size_t)row * SEQ_L;
    float ureg[SEQ_L / NT];
#pragma unroll
    for (int it = 0; it < FFT_N / NT; ++it) {
        const int j = tid + it * NT;
        float v = 0.f;
        if (it < SEQ_L / NT) {
            v = urow[j];
            ureg[it] = v;
        }
        bufA[j] = make_float2(v, 0.f);
    }
    __syncthreads();
    float2* r = fft_stockham<-1>(bufA, bufB, tw, tid);
    float2* o = (r == bufA) ? bufB : bufA;
    const float2* kfr = kf + (size_t)h * FFT_N;
#pragma unroll
    for (int it = 0; it < FFT_N / NT; ++it) {
        const int j = tid + it * NT;
        o[j] = c_mul(r[j], kfr[j]);
    }
    __syncthreads();
    float2* r2 = fft_stockham<+1>(o, r, tw, tid);
    const float Dh = D[h];
    const float invN = 1.0f / (float)FFT_N;
    float* orow = out + (size_t)row * SEQ_L;
#pragma unroll
    for (int it = 0; it < SEQ_L / NT; ++it) {
        const int j = tid + it * NT;
        orow[j] = r2[j].x * invN + ureg[it] * Dh;
    }
}

// ---- Fallback (tiny ws): fused kernel recomputes k_f per block ----
__global__ __launch_bounds__(NT) void conv_fused_kernel(const float* __restrict__ u,
                                                        const float* __restrict__ kin,
                                                        const float* __restrict__ D,
                                                        float* __restrict__ out) {
    __shared__ float2 bufA[FFT_N];
    __shared__ float2 bufB[FFT_N];
    __shared__ float2 kfb[FFT_N];
    __shared__ float2 tw[FFT_N / 2];
    const int tid = threadIdx.x;
    const int row = blockIdx.x;
    const int h = row & (NH - 1);
    init_tw(tw, tid);
    // k FFT
    const float* krow = kin + (size_t)h * SEQ_L;
#pragma unroll
    for (int it = 0; it < FFT_N / NT; ++it) {
        const int j = tid + it * NT;
        float v = (it < SEQ_L / NT) ? krow[j] : 0.f;
        bufA[j] = make_float2(v, 0.f);
    }
    __syncthreads();
    float2* rk = fft_stockham<-1>(bufA, bufB, tw, tid);
#pragma unroll
    for (int it = 0; it < FFT_N / NT; ++it) {
        const int j = tid + it * NT;
        kfb[j] = rk[j];
    }
    __syncthreads();
    // u FFT
    const float* urow = u + (size_t)row * SEQ_L;
    float ureg[SEQ_L / NT];
#pragma unroll
    for (int it = 0; it < FFT_N / NT; ++it) {
        const int j = tid + it * NT;
        float v = 0.f;
        if (it < SEQ_L / NT) {
            v = urow[j];
            ureg[it] = v;
        }
        bufA[j] = make_float2(v, 0.f);
    }
    __syncthreads();
    float2* r = fft_stockham<-1>(bufA, bufB, tw, tid);
    float2* o = (r == bufA) ? bufB : bufA;
#pragma unroll
    for (int it = 0; it < FFT_N / NT; ++it) {
        const int j = tid + it * NT;
        o[j] = c_mul(r[j], kfb[j]);
    }
    __syncthreads();
    float2* r2 = fft_stockham<+1>(o, r, tw, tid);
    const float Dh = D[h];
    const float invN = 1.0f / (float)FFT_N;
    float* orow = out + (size_t)row * SEQ_L;
#pragma unroll
    for (int it = 0; it < SEQ_L / NT; ++it) {
        const int j = tid + it * NT;
        orow[j] = r2[j].x * invN + ureg[it] * Dh;
    }
}

extern "C" void kernel_launch(void* const* d_in, const int* in_sizes, int n_in,
                              void* d_out, int out_size, void* d_ws, size_t ws_size,
                              hipStream_t stream) {
    const float* u = (const float*)d_in[0];
    const float* k = (const float*)d_in[1];
    const float* D = (const float*)d_in[2];
    float* out = (float*)d_out;

    const size_t kf_bytes = (size_t)NH * FFT_N * sizeof(float2);
    if (ws_size >= kf_bytes) {
        float2* kf = (float2*)d_ws;
        kfft_kernel<<<NH, NT, 0, stream>>>(k, kf);
        conv_kernel<<<NB * NH, NT, 0, stream>>>(u, D, kf, out);
    } else {
        conv_fused_kernel<<<NB * NH, NT, 0, stream>>>(u, k, D, out);
    }
}

// Round 2
// 156.833 us; speedup vs baseline: 1.4611x; 1.4611x over previous
//
#include <hip/hip_runtime.h>
#include <math.h>

#define FFT_N   2048
#define HALF_N  1024
#define QUARTER 512
#define SEQ_L   1024
#define NT      256
#define NB      16
#define NH      512

// k_f stash: 512 rows x 2048 complex = 8 MB, static device BSS (graph-safe).
__device__ float2 g_kf[(size_t)NH * FFT_N];

__device__ __forceinline__ float2 c_mul(float2 a, float2 b) {
    return make_float2(a.x * b.x - a.y * b.y, a.x * b.y + a.y * b.x);
}
__device__ __forceinline__ float2 c_add(float2 a, float2 b) {
    return make_float2(a.x + b.x, a.y + b.y);
}
__device__ __forceinline__ float2 c_sub(float2 a, float2 b) {
    return make_float2(a.x - b.x, a.y - b.y);
}

__device__ __forceinline__ void init_tw(float2* tw, int tid) {
#pragma unroll
    for (int it = 0; it < HALF_N / NT; ++it) {
        const int j = tid + it * NT;
        float sv, cv;
        sincosf(-6.283185307179586f * (float)j / (float)FFT_N, &sv, &cv);
        tw[j] = make_float2(cv, sv);
    }
}

// First radix-4 stage (covers radix-2 stages 0,1) for REAL input whose upper
// half (x[1024..2047]) is zero. x0v[it] = x[tid+it*NT], x1v[it] = x[tid+it*NT+512].
// Write-only into dst; syncs at end.
__device__ __forceinline__ void r4_first_real(const float* x0v, const float* x1v,
                                              float2* dst, const float2* tw, int tid) {
#pragma unroll
    for (int it = 0; it < QUARTER / NT; ++it) {
        const int i = tid + it * NT;
        const float x0 = x0v[it];
        const float x1 = x1v[it];
        float2 W1 = tw[i];
        float2 W2 = tw[2 * i];
        float2 W3 = c_mul(W1, W2);
        const float d = x0 - x1;
        dst[4 * i]     = make_float2(x0 + x1, 0.f);
        dst[4 * i + 1] = c_mul(make_float2(x0, -x1), W1);  // (x0 - i*x1)*W1
        dst[4 * i + 2] = make_float2(d * W2.x, d * W2.y);  // (x0 - x1)*W2
        dst[4 * i + 3] = c_mul(make_float2(x0, x1), W3);   // (x0 + i*x1)*W3
    }
    __syncthreads();
}

// Generic radix-4 Stockham stage (covers two radix-2 stages at stride s, 4s).
// SIGN=-1 forward, SIGN=+1 inverse (conjugated twiddles). Syncs at end.
template <int SIGN>
__device__ __forceinline__ void r4_stage(const float2* __restrict__ src,
                                         float2* __restrict__ dst,
                                         const float2* __restrict__ tw,
                                         int s, int tid) {
#pragma unroll
    for (int it = 0; it < QUARTER / NT; ++it) {
        const int i = tid + it * NT;
        const int q = i & (s - 1);
        const int pst = i - q;  // s * p
        float2 x0 = src[i];
        float2 x1 = src[i + QUARTER];
        float2 x2 = src[i + HALF_N];
        float2 x3 = src[i + HALF_N + QUARTER];
        float2 W1 = tw[pst];
        float2 W2 = tw[2 * pst];
        if (SIGN > 0) { W1.y = -W1.y; W2.y = -W2.y; }
        float2 W3 = c_mul(W1, W2);
        float2 e02 = c_add(x0, x2), d02 = c_sub(x0, x2);
        float2 e13 = c_add(x1, x3), d13 = c_sub(x1, x3);
        float2 z0 = c_add(e02, e13), z2 = c_sub(e02, e13);
        float2 t1, t3;
        if (SIGN < 0) {  // -i * d13
            t1 = make_float2(d02.x + d13.y, d02.y - d13.x);
            t3 = make_float2(d02.x - d13.y, d02.y + d13.x);
        } else {         // +i * d13
            t1 = make_float2(d02.x - d13.y, d02.y + d13.x);
            t3 = make_float2(d02.x + d13.y, d02.y - d13.x);
        }
        const int j = q + 4 * pst;
        dst[j]         = z0;
        dst[j + s]     = c_mul(t1, W1);
        dst[j + 2 * s] = c_mul(z2, W2);
        dst[j + 3 * s] = c_mul(t3, W3);
    }
    __syncthreads();
}

// ---- Kernel 1: k_f[h] = FFT_2048(pad(k[h])) -> g_kf ----
__global__ __launch_bounds__(NT) void kfft_kernel(const float* __restrict__ kin) {
    __shared__ float2 A[FFT_N];
    __shared__ float2 B[FFT_N];
    __shared__ float2 tw[HALF_N];
    const int tid = threadIdx.x;
    const int h = blockIdx.x;
    init_tw(tw, tid);
    const float* krow = kin + (size_t)h * SEQ_L;
    float x0v[2], x1v[2];
#pragma unroll
    for (int it = 0; it < 2; ++it) {
        x0v[it] = krow[tid + it * NT];
        x1v[it] = krow[tid + it * NT + QUARTER];
    }
    __syncthreads();  // tw ready
    r4_first_real(x0v, x1v, A, tw, tid);
    float2* src = A;
    float2* dst = B;
#pragma unroll
    for (int s = 4; s <= 256; s *= 4) {
        r4_stage<-1>(src, dst, tw, s, tid);
        float2* t = src; src = dst; dst = t;
    }
    // final radix-2 stage (s=1024, twiddle = 1) fused into global store
    float2* out = g_kf + (size_t)h * FFT_N;
#pragma unroll
    for (int it = 0; it < HALF_N / NT; ++it) {
        const int i = tid + it * NT;
        float2 a = src[i];
        float2 b = src[i + HALF_N];
        out[i]          = c_add(a, b);
        out[i + HALF_N] = c_sub(a, b);
    }
}

// ---- Kernel 2: per (b,h) row: FFT(u) * k_f -> IFFT -> +u*D ----
__global__ __launch_bounds__(NT) void conv_kernel(const float* __restrict__ u,
                                                  const float* __restrict__ D,
                                                  float* __restrict__ out) {
    __shared__ float2 A[FFT_N];
    __shared__ float2 B[FFT_N];
    __shared__ float2 tw[HALF_N];
    const int tid = threadIdx.x;
    const int row = blockIdx.x;  // b*NH + h
    const int h = row & (NH - 1);
    init_tw(tw, tid);
    const float* urow = u + (size_t)row * SEQ_L;
    float ureg[4];
#pragma unroll
    for (int it = 0; it < 4; ++it) ureg[it] = urow[tid + it * NT];
    __syncthreads();  // tw ready
    // forward FFT: first stage straight from registers (upper half is zero-pad)
    float x0v[2] = {ureg[0], ureg[1]};
    float x1v[2] = {ureg[2], ureg[3]};
    r4_first_real(x0v, x1v, A, tw, tid);
    float2* src = A;
    float2* dst = B;
#pragma unroll
    for (int s = 4; s <= 256; s *= 4) {
        r4_stage<-1>(src, dst, tw, s, tid);
        float2* t = src; src = dst; dst = t;
    }
    // fused pass: forward final radix-2 (s=1024) + pointwise * k_f + inverse
    // first radix-4 (s=1, conj twiddles) — all touch the same 4 LDS slots.
    const float2* kfr = g_kf + (size_t)h * FFT_N;
#pragma unroll
    for (int it = 0; it < QUARTER / NT; ++it) {
        const int i = tid + it * NT;
        float2 S0 = src[i];
        float2 S1 = src[i + QUARTER];
        float2 S2 = src[i + HALF_N];
        float2 S3 = src[i + HALF_N + QUARTER];
        // forward final R2: F[i], F[i+512], F[i+1024], F[i+1536]
        float2 F0 = c_add(S0, S2);
        float2 F1 = c_add(S1, S3);
        float2 F2 = c_sub(S0, S2);
        float2 F3 = c_sub(S1, S3);
        // pointwise multiply by k_f
        float2 x0 = c_mul(F0, kfr[i]);
        float2 x1 = c_mul(F1, kfr[i + QUARTER]);
        float2 x2 = c_mul(F2, kfr[i + HALF_N]);
        float2 x3 = c_mul(F3, kfr[i + HALF_N + QUARTER]);
        // inverse radix-4, s=1 (conjugated twiddles, +i)
        float2 W1 = tw[i];     W1.y = -W1.y;
        float2 W2 = tw[2 * i]; W2.y = -W2.y;
        float2 W3 = c_mul(W1, W2);
        float2 e02 = c_add(x0, x2), d02 = c_sub(x0, x2);
        float2 e13 = c_add(x1, x3), d13 = c_sub(x1, x3);
        float2 z0 = c_add(e02, e13), z2 = c_sub(e02, e13);
        float2 t1 = make_float2(d02.x - d13.y, d02.y + d13.x);  // d02 + i*d13
        float2 t3 = make_float2(d02.x + d13.y, d02.y - d13.x);  // d02 - i*d13
        dst[4 * i]     = z0;
        dst[4 * i + 1] = c_mul(t1, W1);
        dst[4 * i + 2] = c_mul(z2, W2);
        dst[4 * i + 3] = c_mul(t3, W3);
    }
    __syncthreads();
    { float2* t = src; src = dst; dst = t; }
#pragma unroll
    for (int s = 4; s <= 256; s *= 4) {
        r4_stage<+1>(src, dst, tw, s, tid);
        float2* t = src; src = dst; dst = t;
    }
    // epilogue: inverse final radix-2 (real part only) + 1/N + u*D
    const float Dh = D[h];
    const float invN = 1.0f / (float)FFT_N;
    float* orow = out + (size_t)row * SEQ_L;
#pragma unroll
    for (int it = 0; it < 4; ++it) {
        const int j = tid + it * NT;
        orow[j] = (src[j].x + src[j + HALF_N].x) * invN + ureg[it] * Dh;
    }
}

extern "C" void kernel_launch(void* const* d_in, const int* in_sizes, int n_in,
                              void* d_out, int out_size, void* d_ws, size_t ws_size,
                              hipStream_t stream) {
    const float* u = (const float*)d_in[0];
    const float* k = (const float*)d_in[1];
    const float* D = (const float*)d_in[2];
    float* out = (float*)d_out;

    kfft_kernel<<<NH, NT, 0, stream>>>(k);
    conv_kernel<<<NB * NH, NT, 0, stream>>>(u, D, out);
}

// Round 3
// 131.542 us; speedup vs baseline: 1.7420x; 1.1923x over previous
//
#include <hip/hip_runtime.h>
#include <math.h>

#define FFT_N   2048
#define HALF_N  1024
#define QUARTER 512
#define SEQ_L   1024
#define NT      256
#define NB      16
#define NH      512

// Bank-conflict padding: one float2 pad per 16 elements.
#define P(x) ((x) + ((x) >> 4))
#define BUF_SZ 2176   // P(2047)=2174
#define TW_SZ  544    // P(511)=542

// k_f stash: 512 rows x 2048 complex = 8 MB, static device BSS (graph-safe).
__device__ float2 g_kf[(size_t)NH * FFT_N];

__device__ __forceinline__ float2 c_mul(float2 a, float2 b) {
    return make_float2(a.x * b.x - a.y * b.y, a.x * b.y + a.y * b.x);
}
__device__ __forceinline__ float2 c_add(float2 a, float2 b) {
    return make_float2(a.x + b.x, a.y + b.y);
}
__device__ __forceinline__ float2 c_sub(float2 a, float2 b) {
    return make_float2(a.x - b.x, a.y - b.y);
}

__device__ __forceinline__ void init_tw(float2* tw, int tid) {
#pragma unroll
    for (int it = 0; it < QUARTER / NT; ++it) {
        const int j = tid + it * NT;
        float sv, cv;
        sincosf(-6.283185307179586f * (float)j / (float)FFT_N, &sv, &cv);
        tw[P(j)] = make_float2(cv, sv);
    }
}

// First radix-4 stage (covers radix-2 stages 0,1) for COMPLEX input whose
// upper half (x[1024..2047]) is zero. x0v[it]=x[tid+it*NT], x1v[it]=x[...+512].
// Write-only into dst; syncs at end.
__device__ __forceinline__ void r4_first(const float2* x0v, const float2* x1v,
                                         float2* dst, const float2* tw, int tid) {
#pragma unroll
    for (int it = 0; it < QUARTER / NT; ++it) {
        const int i = tid + it * NT;
        float2 x0 = x0v[it];
        float2 x1 = x1v[it];
        float2 W1 = tw[P(i)];
        float2 W2 = c_mul(W1, W1);
        float2 W3 = c_mul(W1, W2);
        dst[P(4 * i)]     = c_add(x0, x1);
        float2 a = make_float2(x0.x + x1.y, x0.y - x1.x);  // x0 - i*x1
        dst[P(4 * i + 1)] = c_mul(a, W1);
        dst[P(4 * i + 2)] = c_mul(c_sub(x0, x1), W2);
        float2 b = make_float2(x0.x - x1.y, x0.y + x1.x);  // x0 + i*x1
        dst[P(4 * i + 3)] = c_mul(b, W3);
    }
    __syncthreads();
}

// Generic radix-4 Stockham stage (covers two radix-2 stages at stride s, 2s).
// SIGN=-1 forward, SIGN=+1 inverse (conjugated twiddles). Syncs at end.
template <int SIGN>
__device__ __forceinline__ void r4_stage(const float2* src, float2* dst,
                                         const float2* tw, int s, int tid) {
#pragma unroll
    for (int it = 0; it < QUARTER / NT; ++it) {
        const int i = tid + it * NT;
        const int q = i & (s - 1);
        const int pst = i - q;  // s * p
        float2 x0 = src[P(i)];
        float2 x1 = src[P(i + QUARTER)];
        float2 x2 = src[P(i + HALF_N)];
        float2 x3 = src[P(i + HALF_N + QUARTER)];
        float2 W1 = tw[P(pst)];
        if (SIGN > 0) W1.y = -W1.y;
        float2 W2 = c_mul(W1, W1);
        float2 W3 = c_mul(W1, W2);
        float2 e02 = c_add(x0, x2), d02 = c_sub(x0, x2);
        float2 e13 = c_add(x1, x3), d13 = c_sub(x1, x3);
        float2 z0 = c_add(e02, e13), z2 = c_sub(e02, e13);
        float2 t1, t3;
        if (SIGN < 0) {  // -i * d13
            t1 = make_float2(d02.x + d13.y, d02.y - d13.x);
            t3 = make_float2(d02.x - d13.y, d02.y + d13.x);
        } else {         // +i * d13
            t1 = make_float2(d02.x - d13.y, d02.y + d13.x);
            t3 = make_float2(d02.x + d13.y, d02.y - d13.x);
        }
        const int j = q + 4 * pst;
        dst[P(j)]         = z0;
        dst[P(j + s)]     = c_mul(t1, W1);
        dst[P(j + 2 * s)] = c_mul(z2, W2);
        dst[P(j + 3 * s)] = c_mul(t3, W3);
    }
    __syncthreads();
}

// ---- Kernel 1: k_f[h] = FFT_2048(pad(k[h])) -> g_kf ----
__global__ __launch_bounds__(NT) void kfft_kernel(const float* __restrict__ kin) {
    __shared__ float2 A[BUF_SZ];
    __shared__ float2 B[BUF_SZ];
    __shared__ float2 tw[TW_SZ];
    const int tid = threadIdx.x;
    const int h = blockIdx.x;
    init_tw(tw, tid);
    const float* krow = kin + (size_t)h * SEQ_L;
    float2 x0v[2], x1v[2];
#pragma unroll
    for (int it = 0; it < 2; ++it) {
        x0v[it] = make_float2(krow[tid + it * NT], 0.f);
        x1v[it] = make_float2(krow[tid + it * NT + QUARTER], 0.f);
    }
    __syncthreads();  // tw ready
    r4_first(x0v, x1v, A, tw, tid);
    float2* src = A;
    float2* dst = B;
#pragma unroll
    for (int s = 4; s <= 256; s *= 4) {
        r4_stage<-1>(src, dst, tw, s, tid);
        float2* t = src; src = dst; dst = t;
    }
    // final radix-2 stage (s=1024, twiddle=1) fused into global store
    float2* out = g_kf + (size_t)h * FFT_N;
#pragma unroll
    for (int it = 0; it < HALF_N / NT; ++it) {
        const int i = tid + it * NT;
        float2 a = src[P(i)];
        float2 b = src[P(i + HALF_N)];
        out[i]          = c_add(a, b);
        out[i + HALF_N] = c_sub(a, b);
    }
}

// ---- Kernel 2: two rows (2b,h),(2b+1,h) packed as one complex FFT ----
__global__ __launch_bounds__(NT) void conv_pair_kernel(const float* __restrict__ u,
                                                       const float* __restrict__ D,
                                                       float* __restrict__ out) {
    __shared__ float2 A[BUF_SZ];
    __shared__ float2 B[BUF_SZ];
    __shared__ float2 tw[TW_SZ];
    const int tid = threadIdx.x;
    const int h = blockIdx.x & (NH - 1);
    const int bp = blockIdx.x >> 9;            // batch pair index, 0..7
    const size_t row0 = (size_t)(2 * bp) * NH + h;
    const size_t row1 = row0 + NH;
    init_tw(tw, tid);
    const float* u0 = u + row0 * SEQ_L;
    const float* u1 = u + row1 * SEQ_L;
    float u0reg[4], u1reg[4];
#pragma unroll
    for (int it = 0; it < 4; ++it) {
        u0reg[it] = u0[tid + it * NT];
        u1reg[it] = u1[tid + it * NT];
    }
    __syncthreads();  // tw ready
    // forward FFT of z = u0 + i*u1 (upper half zero): first stage from regs
    float2 x0v[2] = {make_float2(u0reg[0], u1reg[0]), make_float2(u0reg[1], u1reg[1])};
    float2 x1v[2] = {make_float2(u0reg[2], u1reg[2]), make_float2(u0reg[3], u1reg[3])};
    r4_first(x0v, x1v, A, tw, tid);
    float2* src = A;
    float2* dst = B;
#pragma unroll
    for (int s = 4; s <= 256; s *= 4) {
        r4_stage<-1>(src, dst, tw, s, tid);
        float2* t = src; src = dst; dst = t;
    }
    // mid-pass: forward final R2 (s=1024, on the fly) + spectrum split +
    // pointwise *K + repack W = Y1 + i*Y2. Uses K[N-k] = conj(K[k]).
    const float2* kfr = g_kf + (size_t)h * FFT_N;
#pragma unroll
    for (int it = 0; it < 4; ++it) {
        const int k = tid + it * NT;
        if (k == 0) {
            float2 s0 = src[P(0)], s1 = src[P(HALF_N)];
            float2 F0 = c_add(s0, s1);   // Z[0]
            float2 Fn = c_sub(s0, s1);   // Z[1024]
            float2 K0 = kfr[0], Kn = kfr[HALF_N];
            // W[0] = (F0.x*K0) + i*(F0.y*K0)
            float2 Y1 = make_float2(F0.x * K0.x, F0.x * K0.y);
            float2 Y2 = make_float2(F0.y * K0.x, F0.y * K0.y);
            dst[P(0)] = make_float2(Y1.x - Y2.y, Y1.y + Y2.x);
            float2 Z1 = make_float2(Fn.x * Kn.x, Fn.x * Kn.y);
            float2 Z2 = make_float2(Fn.y * Kn.x, Fn.y * Kn.y);
            dst[P(HALF_N)] = make_float2(Z1.x - Z2.y, Z1.y + Z2.x);
        } else {
            float2 Fk = c_add(src[P(k)], src[P(k + HALF_N)]);          // Z[k]
            float2 Fn = c_sub(src[P(HALF_N - k)], src[P(FFT_N - k)]);  // Z[N-k]
            float2 Kk = kfr[k];
            float2 U1 = make_float2(0.5f * (Fk.x + Fn.x), 0.5f * (Fk.y - Fn.y));
            float2 G  = make_float2(Fk.x - Fn.x, Fk.y + Fn.y);
            float2 U2 = make_float2(0.5f * G.y, -0.5f * G.x);
            float2 Y1 = c_mul(U1, Kk);
            float2 Y2 = c_mul(U2, Kk);
            dst[P(k)]         = make_float2(Y1.x - Y2.y, Y1.y + Y2.x);
            dst[P(FFT_N - k)] = make_float2(Y1.x + Y2.y, Y2.x - Y1.y);
        }
    }
    __syncthreads();
    { float2* t = src; src = dst; dst = t; }
    // inverse FFT: full r4 stages s=1..256, final R2 fused into epilogue
#pragma unroll
    for (int s = 1; s <= 256; s *= 4) {
        r4_stage<+1>(src, dst, tw, s, tid);
        float2* t = src; src = dst; dst = t;
    }
    const float Dh = D[h];
    const float invN = 1.0f / (float)FFT_N;
    float* o0 = out + row0 * SEQ_L;
    float* o1 = out + row1 * SEQ_L;
#pragma unroll
    for (int it = 0; it < 4; ++it) {
        const int j = tid + it * NT;
        float2 w = c_add(src[P(j)], src[P(j + HALF_N)]);
        o0[j] = w.x * invN + u0reg[it] * Dh;
        o1[j] = w.y * invN + u1reg[it] * Dh;
    }
}

extern "C" void kernel_launch(void* const* d_in, const int* in_sizes, int n_in,
                              void* d_out, int out_size, void* d_ws, size_t ws_size,
                              hipStream_t stream) {
    const float* u = (const float*)d_in[0];
    const float* k = (const float*)d_in[1];
    const float* D = (const float*)d_in[2];
    float* out = (float*)d_out;

    kfft_kernel<<<NH, NT, 0, stream>>>(k);
    conv_pair_kernel<<<NB * NH / 2, NT, 0, stream>>>(u, D, out);
}

// Round 4
// 118.565 us; speedup vs baseline: 1.9327x; 1.1094x over previous
//
#include <hip/hip_runtime.h>
#include <math.h>

#define NT     256
#define NB     16
#define NH     512
#define SEQ_L  1024
#define FFT_N  2048
#define RS     0.70710678118654752f

// SoA LDS with pad every 16 floats: <=2-way bank aliasing on all stage patterns.
#define P(x) ((x) + ((x) >> 4))
#define BUF_SZ 2176   // P(2047) = 2174

// K in DIF (digit-reversed) order: 512 x 2048 complex = 8 MB BSS (graph-safe).
__device__ float2 g_kf[(size_t)NH * FFT_N];

__device__ __forceinline__ float2 cmul(float2 a, float2 b) {
    return make_float2(a.x * b.x - a.y * b.y, a.x * b.y + a.y * b.x);
}
__device__ __forceinline__ float2 cmulj(float2 a, float2 b) {  // a * conj(b)
    return make_float2(a.x * b.x + a.y * b.y, a.y * b.x - a.x * b.y);
}
__device__ __forceinline__ float2 cadd(float2 a, float2 b) { return make_float2(a.x + b.x, a.y + b.y); }
__device__ __forceinline__ float2 csub(float2 a, float2 b) { return make_float2(a.x - b.x, a.y - b.y); }

// In-place DFT4, natural-order in/out. SIGN=-1 fwd (w=-i), SIGN=+1 inv (w=+i).
template <int SIGN>
__device__ __forceinline__ void dft4(float2 x[4]) {
    float2 s0 = cadd(x[0], x[2]), s1 = csub(x[0], x[2]);
    float2 s2 = cadd(x[1], x[3]), s3 = csub(x[1], x[3]);
    x[0] = cadd(s0, s2);
    x[2] = csub(s0, s2);
    if (SIGN < 0) {
        x[1] = make_float2(s1.x + s3.y, s1.y - s3.x);  // s1 - i*s3
        x[3] = make_float2(s1.x - s3.y, s1.y + s3.x);  // s1 + i*s3
    } else {
        x[1] = make_float2(s1.x - s3.y, s1.y + s3.x);
        x[3] = make_float2(s1.x + s3.y, s1.y - s3.x);
    }
}

// In-place DFT8, natural-order in/out (x[j] = sum_l x[l] w8^(SIGN*j*l)).
template <int SIGN>
__device__ __forceinline__ void dft8(float2 x[8]) {
    float2 e0 = cadd(x[0], x[4]), e1 = cadd(x[1], x[5]);
    float2 e2 = cadd(x[2], x[6]), e3 = cadd(x[3], x[7]);
    float2 o0 = csub(x[0], x[4]), o1 = csub(x[1], x[5]);
    float2 o2 = csub(x[2], x[6]), o3 = csub(x[3], x[7]);
    float2 t1, t2, t3;
    if (SIGN < 0) {
        t1 = make_float2(RS * (o1.x + o1.y), RS * (o1.y - o1.x));   // o1*w8^1
        t2 = make_float2(o2.y, -o2.x);                              // o2*(-i)
        t3 = make_float2(-RS * (o3.x - o3.y), -RS * (o3.x + o3.y)); // o3*w8^3
    } else {
        t1 = make_float2(RS * (o1.x - o1.y), RS * (o1.x + o1.y));
        t2 = make_float2(-o2.y, o2.x);
        t3 = make_float2(RS * (-o3.x - o3.y), RS * (o3.x - o3.y));
    }
    float2 s0 = cadd(e0, e2), s1 = csub(e0, e2), s2 = cadd(e1, e3), s3 = csub(e1, e3);
    x[0] = cadd(s0, s2);
    x[4] = csub(s0, s2);
    float2 u0 = cadd(o0, t2), u1 = csub(o0, t2), u2 = cadd(t1, t3), u3 = csub(t1, t3);
    x[1] = cadd(u0, u2);
    x[5] = csub(u0, u2);
    if (SIGN < 0) {
        x[2] = make_float2(s1.x + s3.y, s1.y - s3.x);
        x[6] = make_float2(s1.x - s3.y, s1.y + s3.x);
        x[3] = make_float2(u1.x + u3.y, u1.y - u3.x);
        x[7] = make_float2(u1.x - u3.y, u1.y + u3.x);
    } else {
        x[2] = make_float2(s1.x - s3.y, s1.y + s3.x);
        x[6] = make_float2(s1.x + s3.y, s1.y - s3.x);
        x[3] = make_float2(u1.x - u3.y, u1.y + u3.x);
        x[7] = make_float2(u1.x + u3.y, u1.y - u3.x);
    }
}

// In-place radix-8 stage, sub-length m (L = 8m). Fwd: butterfly then twiddle
// W_L^(j*q). Inv (adjoint): conj twiddle then butterfly. twstep = 256/m.
template <int SIGN>
__device__ __forceinline__ void stage8(float* re, float* im, const float2* tw,
                                       int t, int m, int twstep) {
    const int q = t & (m - 1);
    const int base = (t - q) * 8 + q;
    int idx[8];
    float2 x[8];
#pragma unroll
    for (int j = 0; j < 8; ++j) {
        idx[j] = P(base + j * m);
        x[j] = make_float2(re[idx[j]], im[idx[j]]);
    }
    const float2 w1 = tw[q * twstep];
    if (SIGN < 0) {
        dft8<-1>(x);
        float2 w = w1;
#pragma unroll
        for (int j = 1; j < 8; ++j) { x[j] = cmul(x[j], w); w = cmul(w, w1); }
    } else {
        float2 w = w1;
#pragma unroll
        for (int j = 1; j < 8; ++j) { x[j] = cmulj(x[j], w); w = cmul(w, w1); }
        dft8<+1>(x);
    }
#pragma unroll
    for (int j = 0; j < 8; ++j) { re[idx[j]] = x[j].x; im[idx[j]] = x[j].y; }
}

// First forward stage (m=256) from registers; z[4..7] are implicit zeros.
__device__ __forceinline__ void stage1_fwd(float* re, float* im, const float2* tw,
                                           int t, const float2 z[4]) {
    float2 e[4] = {z[0], z[1], z[2], z[3]};
    float2 o[4];
    o[0] = z[0];
    o[1] = make_float2(RS * (z[1].x + z[1].y), RS * (z[1].y - z[1].x));
    o[2] = make_float2(z[2].y, -z[2].x);
    o[3] = make_float2(-RS * (z[3].x - z[3].y), -RS * (z[3].x + z[3].y));
    dft4<-1>(e);
    dft4<-1>(o);
    float2 x[8] = {e[0], o[0], e[1], o[1], e[2], o[2], e[3], o[3]};
    const float2 w1 = tw[t];  // q = t, twstep = 1 (written by this thread)
    float2 w = w1;
#pragma unroll
    for (int j = 1; j < 8; ++j) { x[j] = cmul(x[j], w); w = cmul(w, w1); }
#pragma unroll
    for (int j = 0; j < 8; ++j) {
        const int id = P(t + j * 256);
        re[id] = x[j].x;
        im[id] = x[j].y;
    }
}

// ---- Kernel 1: K = DIF(pad(k[h])) stored in DIF order ----
__global__ __launch_bounds__(NT, 8) void kfft_kernel(const float* __restrict__ kin) {
    __shared__ float re[BUF_SZ];
    __shared__ float im[BUF_SZ];
    __shared__ float2 tw[NT];
    const int t = threadIdx.x;
    const int h = blockIdx.x;
    {
        float sv, cv;
        sincosf(-6.283185307179586f * (float)t / (float)FFT_N, &sv, &cv);
        tw[t] = make_float2(cv, sv);
    }
    const float* krow = kin + (size_t)h * SEQ_L;
    float2 z[4];
#pragma unroll
    for (int l = 0; l < 4; ++l) z[l] = make_float2(krow[t + l * 256], 0.f);
    stage1_fwd(re, im, tw, t, z);
    __syncthreads();
    stage8<-1>(re, im, tw, t, 32, 8);
    __syncthreads();
    stage8<-1>(re, im, tw, t, 4, 64);
    __syncthreads();
    // final radix-4 (m=1, twiddle-free) fused with global store
    float2* out = g_kf + (size_t)h * FFT_N;
#pragma unroll
    for (int it = 0; it < 2; ++it) {
        const int b = t + it * NT;
        float2 x[4];
#pragma unroll
        for (int j = 0; j < 4; ++j) {
            const int id = P(4 * b + j);
            x[j] = make_float2(re[id], im[id]);
        }
        dft4<-1>(x);
#pragma unroll
        for (int j = 0; j < 4; ++j) out[4 * b + j] = x[j];
    }
}

// ---- Kernel 2: rows (2bp,h),(2bp+1,h) packed: DIF fwd -> *K -> DIT inv ----
__global__ __launch_bounds__(NT, 8) void conv_pair_kernel(const float* __restrict__ u,
                                                          const float* __restrict__ D,
                                                          float* __restrict__ out) {
    __shared__ float re[BUF_SZ];
    __shared__ float im[BUF_SZ];
    __shared__ float2 tw[NT];
    const int t = threadIdx.x;
    const int h = blockIdx.x & (NH - 1);
    const int bp = blockIdx.x >> 9;
    const size_t row0 = (size_t)(2 * bp) * NH + h;
    const size_t row1 = row0 + NH;
    {
        float sv, cv;
        sincosf(-6.283185307179586f * (float)t / (float)FFT_N, &sv, &cv);
        tw[t] = make_float2(cv, sv);
    }
    const float* u0 = u + row0 * SEQ_L;
    const float* u1 = u + row1 * SEQ_L;
    float ur0[4], ur1[4];
#pragma unroll
    for (int l = 0; l < 4; ++l) {
        ur0[l] = u0[t + l * 256];
        ur1[l] = u1[t + l * 256];
    }
    float2 z[4];
#pragma unroll
    for (int l = 0; l < 4; ++l) z[l] = make_float2(ur0[l], ur1[l]);
    // forward DIF
    stage1_fwd(re, im, tw, t, z);
    __syncthreads();
    stage8<-1>(re, im, tw, t, 32, 8);
    __syncthreads();
    stage8<-1>(re, im, tw, t, 4, 64);
    __syncthreads();
    // fused mid: final fwd radix-4 + elementwise *K + first inv radix-4
    // (all twiddle-free, same 4 LDS slots; spectrum order irrelevant)
    const float2* kfr = g_kf + (size_t)h * FFT_N;
#pragma unroll
    for (int it = 0; it < 2; ++it) {
        const int b = t + it * NT;
        int id[4];
        float2 x[4];
#pragma unroll
        for (int j = 0; j < 4; ++j) {
            id[j] = P(4 * b + j);
            x[j] = make_float2(re[id[j]], im[id[j]]);
        }
        dft4<-1>(x);
#pragma unroll
        for (int j = 0; j < 4; ++j) x[j] = cmul(x[j], kfr[4 * b + j]);
        dft4<+1>(x);
#pragma unroll
        for (int j = 0; j < 4; ++j) { re[id[j]] = x[j].x; im[id[j]] = x[j].y; }
    }
    __syncthreads();
    // inverse DIT (adjoint chain)
    stage8<+1>(re, im, tw, t, 4, 64);
    __syncthreads();
    stage8<+1>(re, im, tw, t, 32, 8);
    __syncthreads();
    // epilogue: inverse m=256 stage, only outputs n = t + 256j, j<4 needed
    float2 x[8];
#pragma unroll
    for (int j = 0; j < 8; ++j) {
        const int id = P(t + j * 256);
        x[j] = make_float2(re[id], im[id]);
    }
    {
        const float2 w1 = tw[t];
        float2 w = w1;
#pragma unroll
        for (int j = 1; j < 8; ++j) { x[j] = cmulj(x[j], w); w = cmul(w, w1); }
    }
    float2 e0 = cadd(x[0], x[4]), e1 = cadd(x[1], x[5]);
    float2 e2 = cadd(x[2], x[6]), e3 = cadd(x[3], x[7]);
    float2 o0 = csub(x[0], x[4]), o1 = csub(x[1], x[5]);
    float2 o2 = csub(x[2], x[6]), o3 = csub(x[3], x[7]);
    float2 t1 = make_float2(RS * (o1.x - o1.y), RS * (o1.x + o1.y));
    float2 t2 = make_float2(-o2.y, o2.x);
    float2 t3 = make_float2(RS * (-o3.x - o3.y), RS * (o3.x - o3.y));
    float2 s0 = cadd(e0, e2), s1 = csub(e0, e2), s2 = cadd(e1, e3), s3 = csub(e1, e3);
    float2 v0 = cadd(o0, t2), v1 = csub(o0, t2), v2 = cadd(t1, t3), v3 = csub(t1, t3);
    float2 y0 = cadd(s0, s2);
    float2 y1 = cadd(v0, v2);
    float2 y2 = make_float2(s1.x - s3.y, s1.y + s3.x);  // s1 + i*s3
    float2 y3 = make_float2(v1.x - v3.y, v1.y + v3.x);  // v1 + i*v3
    const float Dh = D[h];
    const float invN = 1.0f / (float)FFT_N;
    float* o0row = out + row0 * SEQ_L;
    float* o1row = out + row1 * SEQ_L;
    o0row[t]       = y0.x * invN + ur0[0] * Dh;
    o1row[t]       = y0.y * invN + ur1[0] * Dh;
    o0row[t + 256] = y1.x * invN + ur0[1] * Dh;
    o1row[t + 256] = y1.y * invN + ur1[1] * Dh;
    o0row[t + 512] = y2.x * invN + ur0[2] * Dh;
    o1row[t + 512] = y2.y * invN + ur1[2] * Dh;
    o0row[t + 768] = y3.x * invN + ur0[3] * Dh;
    o1row[t + 768] = y3.y * invN + ur1[3] * Dh;
}

extern "C" void kernel_launch(void* const* d_in, const int* in_sizes, int n_in,
                              void* d_out, int out_size, void* d_ws, size_t ws_size,
                              hipStream_t stream) {
    const float* u = (const float*)d_in[0];
    const float* k = (const float*)d_in[1];
    const float* D = (const float*)d_in[2];
    float* out = (float*)d_out;

    kfft_kernel<<<NH, NT, 0, stream>>>(k);
    conv_pair_kernel<<<NB * NH / 2, NT, 0, stream>>>(u, D, out);
}